// Round 1
// 90.581 us; speedup vs baseline: 1.0210x; 1.0210x over previous
//
#include <hip/hip_runtime.h>
#include <stdint.h>

#define NSEG 4096
#define FOUT 64

// Fully fused: per-point linear projection + segment sum, accumulated straight
// into out[NSEG][64]. No workspace, no epilogue kernel.
//
// Each lane owns 8 consecutive points per iteration:
//  - vector loads: 2x int4 (ids), 4x float4 (points)
//  - lane-sequential run accumulation of (sum x0, sum x1, count)
//  - intra-lane run closes stash into one pending record (flushed wave-parallel);
//    2nd close in a chunk (ultra-rare) flushes via serial 64-f fallback
//  - segmented Kogge-Stone scan over lane aggregates; run tails flush
//  - flush = broadcast (seg, a0, a1, c) to all 64 lanes; lane f atomically adds
//    a0*W[0][f] + a1*W[1][f] + c*b[f] into out[seg*64+f] (coalesced 256B burst)
__global__ __launch_bounds__(256) void seg_reduce_fused(
    const float4* __restrict__ x4,   // x viewed as float4 (2 points each)
    const int4*   __restrict__ ids4, // ids viewed as int4
    const float*  __restrict__ W,    // [2][64] row-major
    const float*  __restrict__ b,    // [64]
    float* __restrict__ out,         // [NSEG][64], pre-zeroed
    int nchunk, int nchunk_w)        // chunks of 8 points; wave-rounded bound
{
    const int lane = threadIdx.x & 63;
    const int stride = gridDim.x * blockDim.x;

    // Per-lane epilogue coefficients (768B total, L1-resident broadcast).
    const float w0 = W[lane];
    const float w1 = W[FOUT + lane];
    const float bv = b[lane];

    for (int chunk = blockIdx.x * blockDim.x + threadIdx.x; chunk < nchunk_w; chunk += stride) {
        const bool valid = chunk < nchunk;
        const float vinc = valid ? 1.f : 0.f;

        int4 idA, idB;
        float4 xA, xB, xC, xD;
        if (valid) {
            idA = ids4[2 * chunk];
            idB = ids4[2 * chunk + 1];
            xA = x4[4 * chunk + 0];
            xB = x4[4 * chunk + 1];
            xC = x4[4 * chunk + 2];
            xD = x4[4 * chunk + 3];
        } else {
            idA = make_int4(-1, -1, -1, -1);
            idB = idA;
            xA = make_float4(0.f, 0.f, 0.f, 0.f);
            xB = xC = xD = xA;
        }

        // Lane-local sequential run accumulation over the 8 points.
        int   cur = idA.x;
        float s0 = xA.x, s1 = xA.y, cnt = vinc;

        // One pending closed-run record per lane (flushed wave-parallel below).
        int   pseg = -1;
        float p0 = 0.f, p1 = 0.f, pc = 0.f;

        #define PROC(SEG, X0, X1)                                              \
            if ((SEG) != cur) {                                                \
                if (cur >= 0) {                                                \
                    if (pseg < 0) {                                            \
                        pseg = cur; p0 = s0; p1 = s1; pc = cnt;                \
                    } else {                                                   \
                        /* >=2 intra-chunk closes: ~1e-5 probability; */       \
                        /* serial 64-feature fallback under exec mask. */      \
                        for (int f = 0; f < FOUT; ++f)                         \
                            atomicAdd(&out[(size_t)cur * FOUT + f],            \
                                      s0 * W[f] + s1 * W[FOUT + f] + cnt * b[f]); \
                    }                                                          \
                }                                                              \
                cur = (SEG); s0 = (X0); s1 = (X1); cnt = 1.f;                  \
            } else {                                                           \
                s0 += (X0); s1 += (X1); cnt += vinc;                           \
            }

        PROC(idA.y, xA.z, xA.w)
        PROC(idA.z, xB.x, xB.y)
        PROC(idA.w, xB.z, xB.w)
        PROC(idB.x, xC.x, xC.y)
        PROC(idB.y, xC.z, xC.w)
        PROC(idB.z, xD.x, xD.y)
        PROC(idB.w, xD.z, xD.w)
        #undef PROC

        // Segmented scan across lane aggregates keyed by cur.
        int prev = __shfl_up(cur, 1);
        bool head = (lane == 0) || (prev != cur);
        uint64_t heads = __ballot(head);
        uint64_t below = heads & (~0ull >> (63 - lane));
        int run_start = 63 - __builtin_clzll(below);

        #pragma unroll
        for (int d = 1; d < 64; d <<= 1) {
            float t0 = __shfl_up(s0, d);
            float t1 = __shfl_up(s1, d);
            float tc = __shfl_up(cnt, d);
            if (lane - d >= run_start) { s0 += t0; s1 += t1; cnt += tc; }
        }

        bool tail = (lane == 63) || ((heads >> (lane + 1)) & 1ull);

        // Wave-parallel flush: pendings first, then run tails.
        // Each flush: broadcast record from lane t, all 64 lanes write one
        // feature each -> coalesced 256B atomic burst per record.
        uint64_t pm = __ballot(pseg >= 0);
        while (pm) {
            int t = __ffsll((unsigned long long)pm) - 1;
            pm &= pm - 1;
            int   fs = __shfl(pseg, t);
            float f0 = __shfl(p0, t);
            float f1 = __shfl(p1, t);
            float fc = __shfl(pc, t);
            atomicAdd(&out[(size_t)fs * FOUT + lane], f0 * w0 + f1 * w1 + fc * bv);
        }

        uint64_t tm = __ballot(tail && cur >= 0);
        while (tm) {
            int t = __ffsll((unsigned long long)tm) - 1;
            tm &= tm - 1;
            int   fs = __shfl(cur, t);
            float f0 = __shfl(s0, t);
            float f1 = __shfl(s1, t);
            float fc = __shfl(cnt, t);
            atomicAdd(&out[(size_t)fs * FOUT + lane], f0 * w0 + f1 * w1 + fc * bv);
        }
    }
}

extern "C" void kernel_launch(void* const* d_in, const int* in_sizes, int n_in,
                              void* d_out, int out_size, void* d_ws, size_t ws_size,
                              hipStream_t stream) {
    const float4* x4   = (const float4*)d_in[0];  // [N,2] fp32 -> float4 pairs
    const int4*   ids4 = (const int4*)d_in[1];    // [N] int32 sorted -> int4
    const float*  W    = (const float*)d_in[2];   // [2,64] fp32
    const float*  b    = (const float*)d_in[3];   // [64] fp32
    float* out = (float*)d_out;                   // [4096,64] fp32

    const int n = in_sizes[1];                    // N points (4,000,000; /8 = 500,000)
    const int nchunk = n / 8;                     // 8 points per lane-chunk
    const int nchunk_w = (nchunk + 63) & ~63;

    // Workspace deliberately unused: accumulate directly into the (zeroed)
    // output so the harness's 256 MiB workspace never enters the hot path.
    hipMemsetAsync(d_out, 0, NSEG * FOUT * sizeof(float), stream);

    // 2048 blocks x 256 threads = 524288 lanes >= 500032 chunks: single pass.
    seg_reduce_fused<<<2048, 256, 0, stream>>>(x4, ids4, W, b, out, nchunk, nchunk_w);
}